// Round 4
// baseline (415.526 us; speedup 1.0000x reference)
//
#include <hip/hip_runtime.h>

#define HH 512
#define WW 512
#define HW (512*512)
#define NB 8
#define ND 16
#define RR 5
#define WBLK 64          // tile width (output)
#define HBLK 32          // tile height (output)
#define BR 52            // buffer rows = HBLK + 20
#define AW 74            // first-blur output width = WBLK + 10
#define AR 42            // a,b rows = HBLK + 10
#define PT 75            // LDS pitch (odd -> conflict-free column access)

__device__ __forceinline__ int reflect(int v) {
    if (v < 0) v = -v;
    if (v >= HH) v = 2*HH - 2 - v;
    return v;
}

// ---------------- Prepass: mean_I and 1/(var_I + eps), per image (32x32 tiles) ---------
__global__ __launch_bounds__(256) void img_stats(const float* __restrict__ img,
                                                 float* __restrict__ meanI,
                                                 float* __restrict__ invv) {
    const int EE = 42, Q = 43, PH = 33;
    __shared__ float sI[EE*Q], sI2[EE*Q];
    __shared__ float hI[EE*PH], hI2[EE*PH];

    int blk  = blockIdx.x;
    int tile = blk & 255;
    int b    = blk >> 8;
    int ty0  = (tile >> 4) * 32;
    int tx0  = (tile & 15) * 32;
    const float* ib = img + (size_t)b*HW;
    const float inv121 = 1.0f/121.0f;

    for (int i = threadIdx.x; i < EE*EE; i += 256) {
        int y = i / EE, x = i - y*EE;
        int gy = reflect(ty0 - RR + y);
        int gx = reflect(tx0 - RR + x);
        float v = ib[gy*WW + gx];
        sI [y*Q + x] = v;
        sI2[y*Q + x] = v*v;
    }
    __syncthreads();
    if (threadIdx.x < 168) {
        int t = threadIdx.x;
        int arr = t / 84, r2 = t - arr*84;
        int seg = r2 / 42, row = r2 - seg*42;
        const float* sr = (arr ? sI2 : sI) + row*Q;
        float* dr = (arr ? hI2 : hI) + row*PH;
        int x0 = seg*16;
        float s = 0.f;
        #pragma unroll
        for (int j = 0; j < 10; ++j) s += sr[x0+j];
        #pragma unroll
        for (int x = 0; x < 16; ++x) {
            s += sr[x0+x+10];
            dr[x0+x] = s;
            s -= sr[x0+x];
        }
    }
    __syncthreads();
    {
        int t = threadIdx.x;
        int arr = t >> 7, r2 = t & 127;
        int seg = r2 >> 5, col = r2 & 31;
        const float* src = arr ? hI2 : hI;
        float* dst = arr ? sI2 : sI;
        int y0 = seg*8;
        float s = 0.f;
        #pragma unroll
        for (int j = 0; j < 10; ++j) s += src[(y0+j)*PH+col];
        #pragma unroll
        for (int k = 0; k < 8; ++k) {
            int y = y0 + k;
            s += src[(y+10)*PH+col];
            dst[y*Q+col] = s;
            s -= src[y*PH+col];
        }
    }
    __syncthreads();
    for (int i = threadIdx.x; i < 32*32; i += 256) {
        int y = i >> 5, x = i & 31;
        float mI  = sI [y*Q+x]*inv121;
        float mII = sI2[y*Q+x]*inv121;
        float var = mII - mI*mI;
        int gy = ty0 + y, gx = tx0 + x;
        meanI[(size_t)b*HW + gy*WW + gx] = mI;
        invv [(size_t)b*HW + gy*WW + gx] = 1.0f / (var + 1e-8f);
    }
}

// ---------------- Main fused kernel: one (b,d) channel, one 64x32 tile -----------------
// LDS: hF/hP [52][75]. Slot tricks:
//  - B writes a,b in place at row slot(y) = y + 10*(y>=21)  (y in 0..41)
//  - C writes h-sums of a,b in place at col slot(c) = c + 10*(c>=32) (c in 0..63)
// Disjointness proofs in comments at each phase.
__global__ __launch_bounds__(256, 5) void guided_main(const float* __restrict__ feat,
                                                      const float* __restrict__ img,
                                                      const float* __restrict__ meanI,
                                                      const float* __restrict__ invv,
                                                      float* __restrict__ out) {
    __shared__ float hF[BR*PT];
    __shared__ float hP[BR*PT];

    int blk  = blockIdx.x;
    int tile = blk & 127;        // 8 col-tiles x 16 row-tiles
    int bd   = blk >> 7;
    int b    = bd >> 4;
    int ty0  = (tile >> 3) * HBLK;
    int tx0  = (tile & 7)  * WBLK;

    const float inv121 = 1.0f/121.0f;
    const float* fb  = feat  + (size_t)bd*HW;
    const float* ib  = img   + (size_t)b*HW;
    const float* mIb = meanI + (size_t)b*HW;
    const float* ivb = invv  + (size_t)b*HW;
    const int t = threadIdx.x;

    // ---- Phase A: global rows -> horizontal raw 11-sums -> hF/hP [52][74] ----
    // 4 col-segs (19,19,19,17) x 52 rows = 208 jobs
    if (t < 208) {
        int seg = t / 52, row = t - seg*52;   // lanes: consecutive rows
        int gy = reflect(ty0 - 10 + row);
        const float* fr = fb + gy*WW;
        const float* ir = ib + gy*WW;
        int xb = seg*19;
        float* dF = hF + row*PT + xb;
        float* dP = hP + row*PT + xb;
        float rf[11], rp[11];
        float sf = 0.f, sp = 0.f;
        #pragma unroll
        for (int j = 0; j < 10; ++j) {
            int gx = reflect(tx0 - 10 + xb + j);
            float f = fr[gx], p = f * ir[gx];
            rf[j] = f; rp[j] = p; sf += f; sp += p;
        }
        #pragma unroll
        for (int k = 0; k < 19; ++k) {
            if (xb + k < AW) {
                int gx = reflect(tx0 + xb + k);   // = (tx0-10)+(xb+k)+10
                float f = fr[gx], p = f * ir[gx];
                sf += f; sp += p;
                dF[k] = sf; dP[k] = sp;
                sf -= rf[k%11]; sp -= rp[k%11];
                rf[(k+10)%11] = f; rp[(k+10)%11] = p;
            }
        }
    }
    __syncthreads();

    // ---- Phase B: vertical 11-sums per column + a,b written in place ----
    // 2 row-segs of 21 x 74 cols = 148 jobs.
    // seg0: reads rows 0..30, writes slots 0..20. seg1: reads rows 21..51, writes 31..51.
    // Cross-seg disjoint; within seg1 a thread reads row 31+k then writes the same
    // address (own column) in the same iteration -> safe.
    if (t < 148) {
        int seg = t / 74, col = t - seg*74;   // lanes: consecutive cols
        int ybase = seg*21;
        const float* cF = hF + col;
        const float* cP = hP + col;
        int gx = reflect(tx0 - 5 + col);
        float rf[11], rp[11];
        float sf = 0.f, sp = 0.f;
        #pragma unroll
        for (int j = 0; j < 10; ++j) {
            float f = cF[(ybase+j)*PT], p = cP[(ybase+j)*PT];
            rf[j] = f; rp[j] = p; sf += f; sp += p;
        }
        #pragma unroll
        for (int k = 0; k < 21; ++k) {
            int y = ybase + k;                // a,b row index 0..41
            float f = cF[(y+10)*PT], p = cP[(y+10)*PT];
            sf += f; sp += p;
            float mp  = sf*inv121;
            float cip = sp*inv121;
            int gy = reflect(ty0 - 5 + y);
            float mI = mIb[gy*WW + gx];
            float iv = ivb[gy*WW + gx];
            float a  = (cip - mI*mp) * iv;
            float bb = mp - a*mI;
            int slot = y + 10*seg;
            hF[slot*PT + col] = a;
            hP[slot*PT + col] = bb;
            sf -= rf[k%11]; sp -= rp[k%11];
            rf[(k+10)%11] = f; rp[(k+10)%11] = p;
        }
    }
    __syncthreads();

    // ---- Phase C: horizontal 11-sums of a,b in place (col-slot trick) ----
    // jobs: 2 arrays x 42 rows x 2 col-segs = 168.
    // cseg0: reads cols 0..41, writes 0..31. cseg1: reads 32..73, writes 42..73.
    if (t < 168) {
        int arr = t & 1;
        int idx = t >> 1;                     // 0..83
        int cseg = idx / 42, row = idx - cseg*42;
        int srow = row + ((row >= 21) ? 10 : 0);
        float* rowp = (arr ? hP : hF) + srow*PT;
        int xb = cseg*32;
        float ring[11];
        float s = 0.f;
        #pragma unroll
        for (int j = 0; j < 10; ++j) { float v = rowp[xb+j]; ring[j] = v; s += v; }
        #pragma unroll
        for (int k = 0; k < 32; ++k) {
            float v = rowp[xb+k+10];
            s += v;
            float o = s;
            s -= ring[k%11];
            ring[(k+10)%11] = v;
            rowp[xb + k + 10*cseg] = o;
        }
    }
    __syncthreads();

    // ---- Phase D: vertical 11-sums + combine + store ----
    // 3 row-segs (11,11,10) x 64 cols = 192 jobs
    if (t < 192) {
        int seg = t >> 6, col = t & 63;       // lanes: consecutive cols
        int ybase = seg*11;
        int sc = col + ((col >= 32) ? 10 : 0);
        float ra[11], rb[11];
        float sa = 0.f, sb = 0.f;
        #pragma unroll
        for (int j = 0; j < 10; ++j) {
            int r = ybase + j;
            int sr = r + ((r >= 21) ? 10 : 0);
            float av = hF[sr*PT+sc], bv = hP[sr*PT+sc];
            ra[j] = av; rb[j] = bv; sa += av; sb += bv;
        }
        float* ob = out + (size_t)bd*HW;
        #pragma unroll
        for (int k = 0; k < 11; ++k) {
            if (ybase + k < HBLK) {
                int r = ybase + k + 10;       // <= 41
                int sr = r + ((r >= 21) ? 10 : 0);
                float av = hF[sr*PT+sc], bv = hP[sr*PT+sc];
                sa += av; sb += bv;
                int gy = ty0 + ybase + k, gx = tx0 + col;
                float im = ib[gy*WW + gx];
                ob[gy*WW + gx] = (sa*im + sb)*inv121;
                sa -= ra[k%11]; sb -= rb[k%11];
                ra[(k+10)%11] = av; rb[(k+10)%11] = bv;
            }
        }
    }
}

extern "C" void kernel_launch(void* const* d_in, const int* in_sizes, int n_in,
                              void* d_out, int out_size, void* d_ws, size_t ws_size,
                              hipStream_t stream) {
    const float* feat = (const float*)d_in[0];
    const float* img  = (const float*)d_in[1];
    float* out   = (float*)d_out;
    float* meanI = (float*)d_ws;              // NB*HW floats = 8 MiB
    float* invv  = meanI + (size_t)NB*HW;     // 8 MiB more

    img_stats<<<NB*256, 256, 0, stream>>>(img, meanI, invv);
    guided_main<<<NB*ND*128, 256, 0, stream>>>(feat, img, meanI, invv, out);
}

// Round 5
// 192.979 us; speedup vs baseline: 2.1532x; 2.1532x over previous
//
#include <hip/hip_runtime.h>

#define HH 512
#define WW 512
#define HW (512*512)
#define NB 8
#define ND 16
#define TW 64            // tile width (output)
#define TH 64            // tile height (output)
#define VR 74            // v-sum rows = TH+10
#define RAWC 84          // raw cols = TW+20
#define PT 85            // LDS pitch (odd)

__device__ __forceinline__ int reflect(int v) {
    if (v < 0) v = -v;
    if (v >= HH) v = 2*HH - 2 - v;
    return v;
}

// ---------------- Prepass: mean_I and 1/(var_I + eps), per image (32x32 tiles) ---------
__global__ __launch_bounds__(256) void img_stats(const float* __restrict__ img,
                                                 float* __restrict__ meanI,
                                                 float* __restrict__ invv) {
    const int EE = 42, Q = 43, PH = 33;
    __shared__ float sI[EE*Q], sI2[EE*Q];
    __shared__ float hI[EE*PH], hI2[EE*PH];

    int blk  = blockIdx.x;
    int tile = blk & 255;
    int b    = blk >> 8;
    int ty0  = (tile >> 4) * 32;
    int tx0  = (tile & 15) * 32;
    const float* ib = img + (size_t)b*HW;
    const float inv121 = 1.0f/121.0f;

    for (int i = threadIdx.x; i < EE*EE; i += 256) {
        int y = i / EE, x = i - y*EE;
        int gy = reflect(ty0 - 5 + y);
        int gx = reflect(tx0 - 5 + x);
        float v = ib[gy*WW + gx];
        sI [y*Q + x] = v;
        sI2[y*Q + x] = v*v;
    }
    __syncthreads();
    if (threadIdx.x < 168) {
        int t = threadIdx.x;
        int arr = t / 84, r2 = t - arr*84;
        int seg = r2 / 42, row = r2 - seg*42;
        const float* sr = (arr ? sI2 : sI) + row*Q;
        float* dr = (arr ? hI2 : hI) + row*PH;
        int x0 = seg*16;
        float s = 0.f;
        #pragma unroll
        for (int j = 0; j < 10; ++j) s += sr[x0+j];
        #pragma unroll
        for (int x = 0; x < 16; ++x) {
            s += sr[x0+x+10];
            dr[x0+x] = s;
            s -= sr[x0+x];
        }
    }
    __syncthreads();
    {
        int t = threadIdx.x;
        int arr = t >> 7, r2 = t & 127;
        int seg = r2 >> 5, col = r2 & 31;
        const float* src = arr ? hI2 : hI;
        float* dst = arr ? sI2 : sI;
        int y0 = seg*8;
        float s = 0.f;
        #pragma unroll
        for (int j = 0; j < 10; ++j) s += src[(y0+j)*PH+col];
        #pragma unroll
        for (int k = 0; k < 8; ++k) {
            int y = y0 + k;
            s += src[(y+10)*PH+col];
            dst[y*Q+col] = s;
            s -= src[y*PH+col];
        }
    }
    __syncthreads();
    for (int i = threadIdx.x; i < 32*32; i += 256) {
        int y = i >> 5, x = i & 31;
        float mI  = sI [y*Q+x]*inv121;
        float mII = sI2[y*Q+x]*inv121;
        float var = mII - mI*mI;
        int gy = ty0 + y, gx = tx0 + x;
        meanI[(size_t)b*HW + gy*WW + gx] = mI;
        invv [(size_t)b*HW + gy*WW + gx] = 1.0f / (var + 1e-8f);
    }
}

// ---------------- Main fused kernel: one (b,d) channel, one 64x64 tile -----------------
// Vertical-first separable blurs. LDS: hF/hP [74][85] only.
// Slot maps (all disjointness proven in phase comments):
//   B  : out col hc (0..73) -> slot hc + 10*(hc>=37)
//   C  : out row y  (0..63) -> slot-row y + 10*(y>=32)
//   D  : out col x  (0..63) -> write col x (x<32) or x+20 (x>=32)
__global__ __launch_bounds__(256) void guided_main(const float* __restrict__ feat,
                                                   const float* __restrict__ img,
                                                   const float* __restrict__ meanI,
                                                   const float* __restrict__ invv,
                                                   float* __restrict__ out) {
    __shared__ float hF[VR*PT];
    __shared__ float hP[VR*PT];

    int blk  = blockIdx.x;
    int tile = blk & 63;         // 8x8 tiles of 64x64
    int bd   = blk >> 6;
    int b    = bd >> 4;
    int ty0  = (tile >> 3) * TH;
    int tx0  = (tile & 7)  * TW;

    const float inv121 = 1.0f/121.0f;
    const float* fb  = feat  + (size_t)bd*HW;
    const float* ib  = img   + (size_t)b*HW;
    const float* mIb = meanI + (size_t)b*HW;
    const float* ivb = invv  + (size_t)b*HW;
    const int t = threadIdx.x;

    // ---- Phase A: vertical raw 11-sums of feat and img*feat, coalesced global reads ----
    // 84 cols x 3 row-segs (25,25,24) = 252 threads; lanes = consecutive columns.
    if (t < 252) {
        int seg = t / 84, col = t - seg*84;
        int gx = reflect(tx0 - 10 + col);
        const float* fcol = fb + gx;
        const float* icol = ib + gx;
        int vr0 = seg*25;
        int nout = (seg == 2) ? 24 : 25;
        float rf[11], rp[11];
        float sf = 0.f, sp = 0.f;
        #pragma unroll
        for (int j = 0; j < 10; ++j) {
            int gy = reflect(ty0 - 10 + vr0 + j);
            float f = fcol[gy*WW], im = icol[gy*WW];
            float p = f*im;
            rf[j] = f; rp[j] = p; sf += f; sp += p;
        }
        #pragma unroll
        for (int k = 0; k < 25; ++k) {
            if (k < nout) {
                int vr = vr0 + k;
                int gy = reflect(ty0 + vr);     // = ty0-10 + (vr+10)
                float f = fcol[gy*WW], im = icol[gy*WW];
                float p = f*im;
                sf += f; sp += p;
                hF[vr*PT + col] = sf;
                hP[vr*PT + col] = sp;
                sf -= rf[k%11]; sp -= rp[k%11];
                rf[(k+10)%11] = f; rp[(k+10)%11] = p;
            }
        }
    }
    __syncthreads();

    // ---- Phase B: horizontal 11-sums -> mp, cip written in place at col-slots ----
    // 74 rows x 2 col-segs(37) = 148 threads, each handles F and P.
    // seg0 reads cols 0..46 writes slots 0..36; seg1 reads 37..83 writes 47..83.
    if (t < 148) {
        int seg = t / 74, vr = t - seg*74;
        int xb = seg*37;
        float* rF = hF + vr*PT;
        float* rP = hP + vr*PT;
        float rf[11], rp[11];
        float sf = 0.f, sp = 0.f;
        #pragma unroll
        for (int j = 0; j < 10; ++j) {
            float f = rF[xb+j], p = rP[xb+j];
            rf[j] = f; rp[j] = p; sf += f; sp += p;
        }
        #pragma unroll
        for (int k = 0; k < 37; ++k) {
            int hc = xb + k;
            float f = rF[hc+10], p = rP[hc+10];
            sf += f; sp += p;
            int slot = hc + 10*seg;             // hc + 10*(hc>=37)
            rF[slot] = sf*inv121;               // mp
            rP[slot] = sp*inv121;               // cip
            sf -= rf[k%11]; sp -= rp[k%11];
            rf[(k+10)%11] = f; rp[(k+10)%11] = p;
        }
    }
    __syncthreads();

    // ---- Phase B2: a,b elementwise; coalesced meanI/invv reads; in-place ----
    for (int i = t; i < VR*VR; i += 256) {
        int y = i / VR, x = i - y*VR;
        int slot = x + ((x >= 37) ? 10 : 0);
        float mp  = hF[y*PT + slot];
        float cip = hP[y*PT + slot];
        int gy = reflect(ty0 - 5 + y);
        int gx = reflect(tx0 - 5 + x);
        float mI = mIb[gy*WW + gx];
        float iv = ivb[gy*WW + gx];
        float a  = (cip - mI*mp) * iv;
        hF[y*PT + slot] = a;
        hP[y*PT + slot] = mp - a*mI;
    }
    __syncthreads();

    // ---- Phase C: vertical 11-sums of a,b; in-place at row-slots ----
    // 74 cols x 2 row-segs(32) = 148 threads, both arrays.
    // seg0 reads rows 0..41 writes 0..31; seg1 reads 32..73 writes 42..73.
    if (t < 148) {
        int seg = t / 74, c = t - seg*74;
        int slotc = c + ((c >= 37) ? 10 : 0);
        int y0 = seg*32;
        float ra[11], rb[11];
        float sa = 0.f, sb = 0.f;
        #pragma unroll
        for (int j = 0; j < 10; ++j) {
            float av = hF[(y0+j)*PT + slotc], bv = hP[(y0+j)*PT + slotc];
            ra[j] = av; rb[j] = bv; sa += av; sb += bv;
        }
        #pragma unroll
        for (int k = 0; k < 32; ++k) {
            int y = y0 + k;
            float av = hF[(y+10)*PT + slotc], bv = hP[(y+10)*PT + slotc];
            sa += av; sb += bv;
            int srow = y + 10*seg;              // y + 10*(y>=32)
            hF[srow*PT + slotc] = sa;
            hP[srow*PT + slotc] = sb;
            sa -= ra[k%11]; sb -= rb[k%11];
            ra[(k+10)%11] = av; rb[(k+10)%11] = bv;
        }
    }
    __syncthreads();

    // ---- Phase D: horizontal 11-sums of summed a,b; in place ----
    // 64 rows x 2 arrays x 2 col-segs = 256 threads (100%).
    // seg0 reads slots{0..36,47..51} writes cols 0..31; seg1 reads {32..36,47..83}
    // writes 52..83; all cross/within disjoint (write trails or same-addr-same-iter).
    {
        int arr = t & 1;
        int r2  = t >> 1;                      // 0..127
        int seg = r2 >> 6, row = r2 & 63;
        int srow = row + ((row >= 32) ? 10 : 0);
        float* rp_ = (arr ? hP : hF) + srow*PT;
        int xb = seg*32;
        float ring[11];
        float s = 0.f;
        #pragma unroll
        for (int j = 0; j < 10; ++j) {
            int hc = xb + j;
            int slot = hc + ((hc >= 37) ? 10 : 0);
            float v = rp_[slot];
            ring[j] = v; s += v;
        }
        #pragma unroll
        for (int k = 0; k < 32; ++k) {
            int hc = xb + k + 10;
            int slot = hc + ((hc >= 37) ? 10 : 0);
            float v = rp_[slot];
            s += v;
            int wcol = xb + k + 20*seg;        // 0..31 or 52..83
            rp_[wcol] = s;
            s -= ring[k%11];
            ring[(k+10)%11] = v;
        }
    }
    __syncthreads();

    // ---- Phase D2: combine + coalesced store ----
    float* ob = out + (size_t)bd*HW;
    for (int i = t; i < TH*TW; i += 256) {
        int y = i >> 6, x = i & 63;
        int srow = y + ((y >= 32) ? 10 : 0);
        int wcol = (x < 32) ? x : x + 20;
        float ma = hF[srow*PT + wcol]*inv121;
        float mb = hP[srow*PT + wcol]*inv121;
        int gy = ty0 + y, gx = tx0 + x;
        float im = ib[gy*WW + gx];
        ob[gy*WW + gx] = ma*im + mb;
    }
}

extern "C" void kernel_launch(void* const* d_in, const int* in_sizes, int n_in,
                              void* d_out, int out_size, void* d_ws, size_t ws_size,
                              hipStream_t stream) {
    const float* feat = (const float*)d_in[0];
    const float* img  = (const float*)d_in[1];
    float* out   = (float*)d_out;
    float* meanI = (float*)d_ws;              // NB*HW floats = 8 MiB
    float* invv  = meanI + (size_t)NB*HW;     // 8 MiB more

    img_stats<<<NB*256, 256, 0, stream>>>(img, meanI, invv);
    guided_main<<<NB*ND*64, 256, 0, stream>>>(feat, img, meanI, invv, out);
}

// Round 6
// 174.683 us; speedup vs baseline: 2.3787x; 1.1047x over previous
//
#include <hip/hip_runtime.h>

#define HH 512
#define WW 512
#define HW (512*512)
#define NB 8
#define ND 16
#define TW 64            // tile width (output)
#define TH 32            // tile height (output)
#define VR 42            // v-sum rows = TH+10
#define RAWC 84          // raw cols = TW+20
#define PT 85            // LDS pitch (odd)

__device__ __forceinline__ int reflect(int v) {
    if (v < 0) v = -v;
    if (v >= HH) v = 2*HH - 2 - v;
    return v;
}

// ---------------- Prepass: mean_I and 1/(var_I + eps), per image (32x32 tiles) ---------
__global__ __launch_bounds__(256) void img_stats(const float* __restrict__ img,
                                                 float* __restrict__ meanI,
                                                 float* __restrict__ invv) {
    const int EE = 42, Q = 43, PH = 33;
    __shared__ float sI[EE*Q], sI2[EE*Q];
    __shared__ float hI[EE*PH], hI2[EE*PH];

    int blk  = blockIdx.x;
    int tile = blk & 255;
    int b    = blk >> 8;
    int ty0  = (tile >> 4) * 32;
    int tx0  = (tile & 15) * 32;
    const float* ib = img + (size_t)b*HW;
    const float inv121 = 1.0f/121.0f;

    for (int i = threadIdx.x; i < EE*EE; i += 256) {
        int y = i / EE, x = i - y*EE;
        int gy = reflect(ty0 - 5 + y);
        int gx = reflect(tx0 - 5 + x);
        float v = ib[gy*WW + gx];
        sI [y*Q + x] = v;
        sI2[y*Q + x] = v*v;
    }
    __syncthreads();
    if (threadIdx.x < 168) {
        int t = threadIdx.x;
        int arr = t / 84, r2 = t - arr*84;
        int seg = r2 / 42, row = r2 - seg*42;
        const float* sr = (arr ? sI2 : sI) + row*Q;
        float* dr = (arr ? hI2 : hI) + row*PH;
        int x0 = seg*16;
        float s = 0.f;
        #pragma unroll
        for (int j = 0; j < 10; ++j) s += sr[x0+j];
        #pragma unroll
        for (int x = 0; x < 16; ++x) {
            s += sr[x0+x+10];
            dr[x0+x] = s;
            s -= sr[x0+x];
        }
    }
    __syncthreads();
    {
        int t = threadIdx.x;
        int arr = t >> 7, r2 = t & 127;
        int seg = r2 >> 5, col = r2 & 31;
        const float* src = arr ? hI2 : hI;
        float* dst = arr ? sI2 : sI;
        int y0 = seg*8;
        float s = 0.f;
        #pragma unroll
        for (int j = 0; j < 10; ++j) s += src[(y0+j)*PH+col];
        #pragma unroll
        for (int k = 0; k < 8; ++k) {
            int y = y0 + k;
            s += src[(y+10)*PH+col];
            dst[y*Q+col] = s;
            s -= src[y*PH+col];
        }
    }
    __syncthreads();
    for (int i = threadIdx.x; i < 32*32; i += 256) {
        int y = i >> 5, x = i & 31;
        float mI  = sI [y*Q+x]*inv121;
        float mII = sI2[y*Q+x]*inv121;
        float var = mII - mI*mI;
        int gy = ty0 + y, gx = tx0 + x;
        meanI[(size_t)b*HW + gy*WW + gx] = mI;
        invv [(size_t)b*HW + gy*WW + gx] = 1.0f / (var + 1e-8f);
    }
}

// ---------------- Main fused kernel: one (b,d) channel, one 64x32 tile -----------------
// Vertical-first separable blurs. LDS: hF/hP [42][85] only (28.6 KB -> 5 blocks/CU).
// Slot maps:
//   B : out col hc (0..73) -> slot hc + 10*(hc>=37)   (in-place, proof at phase)
//   C : direct in-place per column (write row y trails read row y+10, thread-private col)
//   D : out col x (0..63) -> write col x (x<32) or x+20 (x>=32)
__global__ __launch_bounds__(256) void guided_main(const float* __restrict__ feat,
                                                   const float* __restrict__ img,
                                                   const float* __restrict__ meanI,
                                                   const float* __restrict__ invv,
                                                   float* __restrict__ out) {
    __shared__ float hF[VR*PT];
    __shared__ float hP[VR*PT];

    int blk  = blockIdx.x;
    int tile = blk & 127;        // 8 col-tiles x 16 row-tiles
    int bd   = blk >> 7;
    int b    = bd >> 4;
    int ty0  = (tile >> 3) * TH;
    int tx0  = (tile & 7)  * TW;

    const float inv121 = 1.0f/121.0f;
    const float* fb  = feat  + (size_t)bd*HW;
    const float* ib  = img   + (size_t)b*HW;
    const float* mIb = meanI + (size_t)b*HW;
    const float* ivb = invv  + (size_t)b*HW;
    const int t = threadIdx.x;

    // ---- Phase A: vertical raw 11-sums of feat and img*feat, coalesced global reads ----
    // 84 cols x 3 row-segs (14 outputs each) = 252 threads; lanes = consecutive columns.
    if (t < 252) {
        int seg = t / 84, col = t - seg*84;
        int gx = reflect(tx0 - 10 + col);
        const float* fcol = fb + gx;
        const float* icol = ib + gx;
        int vr0 = seg*14;
        float rf[11], rp[11];
        float sf = 0.f, sp = 0.f;
        #pragma unroll
        for (int j = 0; j < 10; ++j) {
            int gy = reflect(ty0 - 10 + vr0 + j);
            float f = fcol[gy*WW], im = icol[gy*WW];
            float p = f*im;
            rf[j] = f; rp[j] = p; sf += f; sp += p;
        }
        #pragma unroll
        for (int k = 0; k < 14; ++k) {
            int vr = vr0 + k;
            int gy = reflect(ty0 + vr);     // = ty0-10 + (vr+10)
            float f = fcol[gy*WW], im = icol[gy*WW];
            float p = f*im;
            sf += f; sp += p;
            hF[vr*PT + col] = sf;
            hP[vr*PT + col] = sp;
            sf -= rf[k%11]; sp -= rp[k%11];
            rf[(k+10)%11] = f; rp[(k+10)%11] = p;
        }
    }
    __syncthreads();

    // ---- Phase B: horizontal 11-sums -> mp, cip written in place at col-slots ----
    // 42 rows x 2 col-segs(37) x 2 arrays = 168 threads.
    // seg0 reads cols 0..46 writes slots 0..36; seg1 reads 37..83 writes 47..83
    // (seg1 write addr == its same-iteration read addr, read-then-write, same thread).
    if (t < 168) {
        int arr = t & 1;
        int j2  = t >> 1;                    // 0..83
        int seg = j2 / 42, vr = j2 - seg*42;
        int xb = seg*37;
        float* rA = (arr ? hP : hF) + vr*PT;
        float ring[11];
        float s = 0.f;
        #pragma unroll
        for (int j = 0; j < 10; ++j) {
            float v = rA[xb+j];
            ring[j] = v; s += v;
        }
        #pragma unroll
        for (int k = 0; k < 37; ++k) {
            int hc = xb + k;
            float v = rA[hc+10];
            s += v;
            rA[hc + 10*seg] = s*inv121;      // mp or cip
            s -= ring[k%11];
            ring[(k+10)%11] = v;
        }
    }
    __syncthreads();

    // ---- Phase B2: a,b elementwise; coalesced meanI/invv reads; in-place at slots ----
    for (int i = t; i < VR*74; i += 256) {
        int y = i / 74, x = i - y*74;
        int slot = x + ((x >= 37) ? 10 : 0);
        float mp  = hF[y*PT + slot];
        float cip = hP[y*PT + slot];
        int gy = reflect(ty0 - 5 + y);
        int gx = reflect(tx0 - 5 + x);
        float mI = mIb[gy*WW + gx];
        float iv = ivb[gy*WW + gx];
        float a  = (cip - mI*mp) * iv;
        hF[y*PT + slot] = a;
        hP[y*PT + slot] = mp - a*mI;
    }
    __syncthreads();

    // ---- Phase C: vertical 11-sums of a,b; direct in-place (thread-private column) ----
    // 74 cols x 2 arrays = 148 threads; reads rows 0..41, writes rows 0..31;
    // write row y happens after reading row y+10 -> no hazard.
    if (t < 148) {
        int arr = t & 1;
        int c   = t >> 1;                    // 0..73
        int slotc = c + ((c >= 37) ? 10 : 0);
        float* A = (arr ? hP : hF);
        float ring[11];
        float s = 0.f;
        #pragma unroll
        for (int j = 0; j < 10; ++j) {
            float v = A[j*PT + slotc];
            ring[j] = v; s += v;
        }
        #pragma unroll
        for (int k = 0; k < 32; ++k) {
            float v = A[(k+10)*PT + slotc];
            s += v;
            A[k*PT + slotc] = s;
            s -= ring[k%11];
            ring[(k+10)%11] = v;
        }
    }
    __syncthreads();

    // ---- Phase D: horizontal 11-sums of summed a,b; in place ----
    // 32 rows x 2 arrays x 2 col-segs = 128 threads.
    // seg0 reads slots{0..36,47..51} writes cols 0..31; seg1 reads {32..36,47..83}
    // writes 52..83; cross-disjoint, within-thread write trails read by 10.
    if (t < 128) {
        int arr = t & 1;
        int r2  = t >> 1;                    // 0..63
        int seg = r2 >> 5, row = r2 & 31;
        float* rp_ = (arr ? hP : hF) + row*PT;
        int xb = seg*32;
        float ring[11];
        float s = 0.f;
        #pragma unroll
        for (int j = 0; j < 10; ++j) {
            int hc = xb + j;
            int slot = hc + ((hc >= 37) ? 10 : 0);
            float v = rp_[slot];
            ring[j] = v; s += v;
        }
        #pragma unroll
        for (int k = 0; k < 32; ++k) {
            int hc = xb + k + 10;
            int slot = hc + ((hc >= 37) ? 10 : 0);
            float v = rp_[slot];
            s += v;
            int wcol = xb + k + 20*seg;      // 0..31 or 52..83
            rp_[wcol] = s;
            s -= ring[k%11];
            ring[(k+10)%11] = v;
        }
    }
    __syncthreads();

    // ---- Phase D2: combine + coalesced store ----
    float* ob = out + (size_t)bd*HW;
    for (int i = t; i < TH*TW; i += 256) {
        int y = i >> 6, x = i & 63;
        int wcol = (x < 32) ? x : x + 20;
        float ma = hF[y*PT + wcol]*inv121;
        float mb = hP[y*PT + wcol]*inv121;
        int gy = ty0 + y, gx = tx0 + x;
        float im = ib[gy*WW + gx];
        ob[gy*WW + gx] = ma*im + mb;
    }
}

extern "C" void kernel_launch(void* const* d_in, const int* in_sizes, int n_in,
                              void* d_out, int out_size, void* d_ws, size_t ws_size,
                              hipStream_t stream) {
    const float* feat = (const float*)d_in[0];
    const float* img  = (const float*)d_in[1];
    float* out   = (float*)d_out;
    float* meanI = (float*)d_ws;              // NB*HW floats = 8 MiB
    float* invv  = meanI + (size_t)NB*HW;     // 8 MiB more

    img_stats<<<NB*256, 256, 0, stream>>>(img, meanI, invv);
    guided_main<<<NB*ND*128, 256, 0, stream>>>(feat, img, meanI, invv, out);
}